// Round 10
// baseline (97.390 us; speedup 1.0000x reference)
//
#include <hip/hip_runtime.h>

// SE block: gap = mean(relation, spatial); bottle = relu(gap@W1^T + b1);
// gate = sigmoid(bottle@W2^T + b2); scale = float(int64(gate)); out = relation*scale.
// Shapes: relation [B=64, HEADS=16, 256, 256] fp32; W1 [4,16]; b1 [4]; W2 [16,4]; b2 [16].
//
// 3 pure phases (R8 showed mixed read+write streams lose ~20% BW; R5/R7 showed
// in-kernel sync loses 2-3x; R3 showed split phases = 94 us):
//   1) speculative zero-fill of `out`  (pure write, no deps, fill-rate ~7 TB/s)
//   2) GAP reduction                   (pure read)
//   3) tiny MLP + rare fixup rewrite   (scale = float(int64(sigmoid)) is 0 or 1;
//      0 for any non-degenerate input -> phase 3 is ~3 us, no traffic)

#define NB 64
#define NHEADS 16
#define NPLANES (NB * NHEADS)     // 1024 planes
#define HW 65536                  // elements per plane
#define HW4 16384                 // float4s per plane
#define GAP_THREADS 512           // 8 waves/block, 1024 blocks
#define FILL_BLOCKS 2048
#define FILL_CHUNK4 (HW4 * NPLANES / FILL_BLOCKS)   // 8192 f32x4 per fill block

typedef float f32x4 __attribute__((ext_vector_type(4)));

// ---------------- Phase 1: speculative zero-fill of out ----------------
__global__ __launch_bounds__(256) void se_zero_kernel(float* __restrict__ out) {
    f32x4* __restrict__ dst = (f32x4*)out + (size_t)blockIdx.x * FILL_CHUNK4;
    const f32x4 z = {0.0f, 0.0f, 0.0f, 0.0f};
    #pragma unroll 8
    for (int i = threadIdx.x; i < FILL_CHUNK4; i += 256)
        __builtin_nontemporal_store(z, dst + i);
}

// ---------------- Phase 2: per-plane global average pool ----------------
__global__ __launch_bounds__(GAP_THREADS) void se_gap_kernel(const float* __restrict__ rel,
                                                             float* __restrict__ gap) {
    const int p = blockIdx.x;                       // plane id = b*16 + h
    const f32x4* __restrict__ src = (const f32x4*)(rel + (size_t)p * HW);
    float s = 0.0f;
    #pragma unroll 4
    for (int i = threadIdx.x; i < HW4; i += GAP_THREADS) {
        f32x4 v = __builtin_nontemporal_load(src + i);
        s += (v.x + v.y) + (v.z + v.w);
    }
    #pragma unroll
    for (int off = 32; off > 0; off >>= 1)
        s += __shfl_down(s, off, 64);
    __shared__ float ws[GAP_THREADS / 64];
    const int wave = threadIdx.x >> 6;
    if ((threadIdx.x & 63) == 0) ws[wave] = s;
    __syncthreads();
    if (threadIdx.x == 0) {
        float t = 0.0f;
        #pragma unroll
        for (int w = 0; w < GAP_THREADS / 64; ++w) t += ws[w];
        gap[p] = t * (1.0f / (float)HW);
    }
}

// ------- Phase 3: per-plane MLP (uniform, scalarized); fixup only when scale != 0 -------
__global__ __launch_bounds__(256) void se_fixup_kernel(const float* __restrict__ rel,
                                                       const float* __restrict__ gap,
                                                       const float* __restrict__ W1,
                                                       const float* __restrict__ b1,
                                                       const float* __restrict__ W2,
                                                       const float* __restrict__ b2,
                                                       float* __restrict__ out) {
    const int p = blockIdx.x;                        // plane id = b*16 + h
    const int b = p >> 4;
    const int h = p & (NHEADS - 1);

    // block-uniform MLP: compiler scalarizes (all threads compute the same thing)
    float bot[4];
    #pragma unroll
    for (int c = 0; c < 4; ++c) {
        float a = b1[c];
        #pragma unroll
        for (int k = 0; k < NHEADS; ++k) a += gap[b * NHEADS + k] * W1[c * NHEADS + k];
        bot[c] = fmaxf(a, 0.0f);
    }
    float a = b2[h];
    #pragma unroll
    for (int c = 0; c < 4; ++c) a += bot[c] * W2[h * 4 + c];
    const float gate = 1.0f / (1.0f + expf(-a));     // sigmoid
    const float sc = (float)(long long)gate;         // astype(int64) trunc
    if (sc == 0.0f) return;                          // out already zeroed in phase 1

    // rare path: rewrite this plane as rel * sc
    const size_t base4 = (size_t)p * HW4;
    const f32x4* __restrict__ src = (const f32x4*)rel + base4;
    f32x4* __restrict__ dst = (f32x4*)out + base4;
    #pragma unroll 4
    for (int i = threadIdx.x; i < HW4; i += 256) {
        f32x4 v = __builtin_nontemporal_load(src + i);
        v *= sc;
        __builtin_nontemporal_store(v, dst + i);
    }
}

extern "C" void kernel_launch(void* const* d_in, const int* in_sizes, int n_in,
                              void* d_out, int out_size, void* d_ws, size_t ws_size,
                              hipStream_t stream) {
    const float* rel = (const float*)d_in[0];
    const float* W1  = (const float*)d_in[1];
    const float* b1  = (const float*)d_in[2];
    const float* W2  = (const float*)d_in[3];
    const float* b2  = (const float*)d_in[4];
    float* out = (float*)d_out;

    float* gap = (float*)d_ws;                    // NPLANES floats

    se_zero_kernel<<<FILL_BLOCKS, 256, 0, stream>>>(out);
    se_gap_kernel<<<NPLANES, GAP_THREADS, 0, stream>>>(rel, gap);
    se_fixup_kernel<<<NPLANES, 256, 0, stream>>>(rel, gap, W1, b1, W2, b2, out);
}

// Round 11
// 93.847 us; speedup vs baseline: 1.0378x; 1.0378x over previous
//
#include <hip/hip_runtime.h>

// SE block: gap = mean(relation, spatial); bottle = relu(gap@W1^T + b1);
// gate = sigmoid(bottle@W2^T + b2); scale = float(int64(gate)); out = relation*scale.
// Shapes: relation [B=64, HEADS=16, 256, 256] fp32; W1 [4,16]; b1 [4]; W2 [16,4]; b2 [16].
//
// FINAL (revert to best-measured R3 structure, 94.0 us):
//   Phase 1: pure-read GAP (1024 blocks x 512 thr, f32x4 nontemporal loads)
//   Phase 2: fused block-uniform scalarized MLP + write phase (8192 blocks);
//            scale = float(int64(sigmoid)) is exactly 0.0 or 1.0 -> when 0 the
//            write path stores zeros without re-reading `relation`.
// Measured dead ends: 3-phase split (+3.4us, boundary cost ~4-6us each),
// interleaved read+write (-20% BW), in-kernel cross-block sync (2-3x worse),
// finer chunking (+4us), temporal loads (null). Ceiling: 536 MB mandatory
// traffic at ~6.6-7.0 TB/s dedicated-stream rates + 1 boundary = ~92-94 us.

#define NB 64
#define NHEADS 16
#define NPLANES (NB * NHEADS)     // 1024 planes
#define HW 65536                  // elements per plane
#define HW4 16384                 // float4s per plane
#define GAP_THREADS 512           // 8 waves/block -> 32 waves/CU at 1024 blocks
#define MUL_CHUNKS 8              // blocks per plane in multiply kernel
#define CHUNK4 (HW4 / MUL_CHUNKS) // 2048 float4s per block

typedef float f32x4 __attribute__((ext_vector_type(4)));  // native vector for nontemporal builtins

// ---------------- Kernel 1: per-plane global average pool ----------------
__global__ __launch_bounds__(GAP_THREADS) void se_gap_kernel(const float* __restrict__ rel,
                                                             float* __restrict__ gap) {
    const int p = blockIdx.x;                       // plane id = b*16 + h
    const f32x4* __restrict__ src = (const f32x4*)(rel + (size_t)p * HW);
    float s = 0.0f;
    #pragma unroll 4
    for (int i = threadIdx.x; i < HW4; i += GAP_THREADS) {
        f32x4 v = __builtin_nontemporal_load(src + i);    // streaming read, no reuse
        s += (v.x + v.y) + (v.z + v.w);
    }
    // wave (64-lane) down reduce
    #pragma unroll
    for (int off = 32; off > 0; off >>= 1)
        s += __shfl_down(s, off, 64);
    __shared__ float ws[GAP_THREADS / 64];
    const int wave = threadIdx.x >> 6;
    if ((threadIdx.x & 63) == 0) ws[wave] = s;
    __syncthreads();
    if (threadIdx.x == 0) {
        float t = 0.0f;
        #pragma unroll
        for (int w = 0; w < GAP_THREADS / 64; ++w) t += ws[w];
        gap[p] = t * (1.0f / (float)HW);
    }
}

// ------- Kernel 2: fused SE-MLP (block-uniform, scalarized) + broadcast multiply -------
__global__ __launch_bounds__(256) void se_mlp_mul_kernel(const float* __restrict__ rel,
                                                         const float* __restrict__ gap,
                                                         const float* __restrict__ W1,
                                                         const float* __restrict__ b1,
                                                         const float* __restrict__ W2,
                                                         const float* __restrict__ b2,
                                                         float* __restrict__ out) {
    const int p     = blockIdx.x >> 3;              // plane id = b*16 + h
    const int chunk = blockIdx.x & (MUL_CHUNKS - 1);
    const int b = p >> 4;
    const int h = p & (NHEADS - 1);

    // --- tiny SE MLP, all operands block-uniform -> scalar loads + uniform VALU ---
    float bot[4];
    #pragma unroll
    for (int c = 0; c < 4; ++c) {
        float acc = b1[c];
        #pragma unroll
        for (int k = 0; k < NHEADS; ++k) acc += gap[b * NHEADS + k] * W1[c * NHEADS + k];
        bot[c] = fmaxf(acc, 0.0f);
    }
    float acc = b2[h];
    #pragma unroll
    for (int c = 0; c < 4; ++c) acc += bot[c] * W2[h * 4 + c];
    const float gate = 1.0f / (1.0f + expf(-acc));            // sigmoid
    const float s = (float)(long long)gate;                   // astype(int64) trunc

    const size_t base4 = (size_t)p * HW4 + (size_t)chunk * CHUNK4;
    f32x4* __restrict__ dst = (f32x4*)out + base4;
    if (s == 0.0f) {
        // output exactly zero; skip reading relation entirely
        const f32x4 z = {0.0f, 0.0f, 0.0f, 0.0f};
        for (int i = threadIdx.x; i < CHUNK4; i += 256)
            __builtin_nontemporal_store(z, dst + i);
    } else {
        const f32x4* __restrict__ src = (const f32x4*)rel + base4;
        for (int i = threadIdx.x; i < CHUNK4; i += 256) {
            f32x4 v = __builtin_nontemporal_load(src + i);
            v *= s;
            __builtin_nontemporal_store(v, dst + i);
        }
    }
}

extern "C" void kernel_launch(void* const* d_in, const int* in_sizes, int n_in,
                              void* d_out, int out_size, void* d_ws, size_t ws_size,
                              hipStream_t stream) {
    const float* rel = (const float*)d_in[0];
    const float* W1  = (const float*)d_in[1];
    const float* b1  = (const float*)d_in[2];
    const float* W2  = (const float*)d_in[3];
    const float* b2  = (const float*)d_in[4];
    float* out = (float*)d_out;

    float* gap = (float*)d_ws;                    // NPLANES floats

    se_gap_kernel<<<NPLANES, GAP_THREADS, 0, stream>>>(rel, gap);
    se_mlp_mul_kernel<<<NPLANES * MUL_CHUNKS, 256, 0, stream>>>(rel, gap, W1, b1, W2, b2, out);
}